// Round 12
// baseline (42.272 us; speedup 1.0000x reference)
//
#include <hip/hip_runtime.h>
#include <cfloat>

// Problem constants (from reference): B=8, C=2, H=256, W=256
#define BB 8
#define CC 2
#define HH 256
#define WW 256

typedef unsigned long long ull;

static constexpr float EDT_INF = 1e4f;          // matches reference INF
static constexpr int   NPIX    = BB * HH * WW;  // 524288
#define NCOL (BB * WW)                          // 2048 worker blocks
#define FGRID (NCOL + 1)                        // + 1 reducer block

// ---------------------------------------------------------------------------
// Distance^2 to nearest SET bit of zm (the zeros of the selected field),
// reproducing the reference f32 scan exactly (sentinels 1e4+pos+1 /
// 1e4+256-pos, g = fminf(fwd,bwd), return g*g).
__device__ __forceinline__ float hdist2(const ull* zm, int pos) {
    float fwd = EDT_INF + (float)(pos + 1);
    {
        int k = pos - 1;
        if (k >= 0) {
            int w = k >> 6;
            ull t = zm[w] & (~0ULL >> (63 - (k & 63)));
            for (;;) {
                if (t) { int j = (w << 6) + 63 - __builtin_clzll(t); fwd = (float)(pos - j); break; }
                if (--w < 0) break;
                t = zm[w];
            }
        }
    }
    float bwd = EDT_INF + (float)(256 - pos);
    {
        int k = pos + 1;
        if (k < 256) {
            int w = k >> 6;
            ull t = zm[w] & (~0ULL << (k & 63));
            for (;;) {
                if (t) { int j = (w << 6) + __builtin_ctzll(t); bwd = (float)(j - pos); break; }
                if (++w >= 4) break;
                t = zm[w];
            }
        }
    }
    float g = fminf(fwd, bwd);
    return g * g;
}

// Nearest SET bit distance (int), large sentinel when none.
__device__ __forceinline__ int nearest_set(const ull* zm, int pos) {
    int best = 1 << 20;
    {
        int k = pos - 1;
        if (k >= 0) {
            int w = k >> 6;
            ull t = zm[w] & (~0ULL >> (63 - (k & 63)));
            for (;;) {
                if (t) { int j = (w << 6) + 63 - __builtin_clzll(t); best = pos - j; break; }
                if (--w < 0) break;
                t = zm[w];
            }
        }
    }
    {
        int k = pos + 1;
        if (k < 256) {
            int w = k >> 6;
            ull t = zm[w] & (~0ULL << (k & 63));
            for (;;) {
                if (t) { int j = (w << 6) + __builtin_ctzll(t); best = min(best, j - pos); break; }
                if (++w >= 4) break;
                t = zm[w];
            }
        }
    }
    return best;
}

// ---------------------------------------------------------------------------
// K1: build ROW masks (coalesced: lanes across w) + per-block tmin partials.
// Also resets the partialB sentinel slots for this call (runs before k_fused
// in stream order; every column partial is >= 256*sqrt(1e-9) > 0, so -1 is
// an unreachable sentinel).
__global__ void k_masks(const float* __restrict__ preds,
                        const int*   __restrict__ target,
                        ull* __restrict__ mPC, ull* __restrict__ mGT0,
                        ull* __restrict__ mG255, int* __restrict__ tminPart,
                        float* __restrict__ partialB) {
    const int blk = blockIdx.x;
    const int b  = blk >> 5;               // image
    const int ig = blk & 31;               // 8-row group
    const int wv = threadIdx.x >> 6;       // word index 0..3
    const int ln = threadIdx.x & 63;
    const int w  = (wv << 6) | ln;

    if (threadIdx.x < 8) partialB[blk * 8 + threadIdx.x] = -1.0f;

    int tmin = 0x7fffffff;
#pragma unroll
    for (int r = 0; r < 8; ++r) {
        int i = ig * 8 + r;
        float a0 = preds[((size_t)b * CC + 0) * HH * WW + (size_t)i * WW + w];
        float a1 = preds[((size_t)b * CC + 1) * HH * WW + (size_t)i * WW + w];
        bool pc = (a1 > a0);               // argmax over C=2, ties -> class 0
        int tv = target[((size_t)b * HH + i) * WW + w];
        tmin = min(tmin, tv);
        ull bp = __ballot(pc);
        ull b0 = __ballot(tv > 0);
        ull b2 = __ballot(tv == 255);
        if (ln == 0) {
            size_t midx = ((size_t)b * HH + i) * 4 + wv;
            mPC[midx] = bp; mGT0[midx] = b0; mG255[midx] = b2;
        }
    }
    for (int off = 32; off > 0; off >>= 1) tmin = min(tmin, __shfl_down(tmin, off));
    __shared__ int swv[4];
    if (ln == 0) swv[wv] = tmin;
    __syncthreads();
    if (threadIdx.x == 0)
        tminPart[blk] = min(min(swv[0], swv[1]), min(swv[2], swv[3]));
}

// ---------------------------------------------------------------------------
// Per-column fused EDT + final math -> block-wide partial sum for column
// (b,j). i = threadIdx.x = row. Uses caller-provided LDS buffers.
__device__ __forceinline__ float column_partial(
        const int* __restrict__ target, int b, int j, int i, int tmin,
        const ull wp[4], const ull wg[4],
        float* s_p, float* s_g, ull* cshP, ull* cshG, float* sws) {
    const int wv = i >> 6, ln = i & 63;
    const bool pc = (wp[j >> 6] >> (j & 63)) & 1ULL;
    const bool gt = (wg[j >> 6] >> (j & 63)) & 1ULL;

    // own-polarity zero-masks
    ull zp[4], zg[4];
#pragma unroll
    for (int k = 0; k < 4; ++k) {
        zp[k] = pc ? ~wp[k] : wp[k];
        zg[k] = gt ? ~wg[k] : wg[k];
    }
    s_p[i] = hdist2(zp, j);
    s_g[i] = hdist2(zg, j);
    {
        ull bp = __ballot(pc);
        ull bg = __ballot(gt);
        if (ln == 0) { cshP[wv] = bp; cshG[wv] = bg; }
    }
    __syncthreads();

    // column opposite-polarity masks
    ull cp[4], cgm[4];
#pragma unroll
    for (int k = 0; k < 4; ++k) {
        ull P = cshP[k], G = cshG[k];
        cp[k]  = pc ? ~P : P;
        cgm[k] = gt ? ~G : G;
    }
    const int dvp = nearest_set(cp, i);
    const int dvg = nearest_set(cgm, i);

    // pc vertical search, pruned (opposite rows give exactly d^2 candidates)
    float mn = s_p[i];
    {
        int dmax = min(dvp, HH);
        for (int d = 1; d < dmax; ++d) {
            float dd = (float)(d * d);
            if (dd >= mn) break;
            int kl = i - d, kr = i + d;
            if (kl >= 0) mn = fminf(mn, dd + s_p[kl]);
            if (kr < HH) mn = fminf(mn, dd + s_p[kr]);
        }
        float dv = (float)dvp;
        mn = fminf(mn, dv * dv);
    }
    float pd = sqrtf(mn);

    // gt vertical search, pruned
    float mg = s_g[i];
    {
        int dmax = min(dvg, HH);
        for (int d = 1; d < dmax; ++d) {
            float dd = (float)(d * d);
            if (dd >= mg) break;
            int kl = i - d, kr = i + d;
            if (kl >= 0) mg = fminf(mg, dd + s_g[kl]);
            if (kr < HH) mg = fminf(mg, dd + s_g[kr]);
        }
        float dv = (float)dvg;
        mg = fminf(mg, dv * dv);
    }
    float gd = sqrtf(mg);

    // final elementwise math (reference op order)
    int tv = target[((size_t)b * HH + i) * WW + j];
    if (tv == 255) tv = tmin;
    float gtv = (float)tv;
    float pcv = pc ? 1.0f : 0.0f;
    float err  = fabsf(gtv - pcv);
    float dist = sqrtf(pd * pd + gd * gd);
    float mult = sqrtf(err * dist + 1e-9f);

    // deterministic block sum: wave shfl-add + fixed-order 4-term merge
    for (int off = 32; off > 0; off >>= 1) mult += __shfl_down(mult, off);
    if (ln == 0) sws[wv] = mult;
    __syncthreads();
    return ((sws[0] + sws[1]) + sws[2]) + sws[3];
}

// ---------------------------------------------------------------------------
// K2: 2048 worker blocks (R8 structure, 1 column each, no atomics) + 1
// reducer block that spin-waits on the 2048 sentinel slots (distinct
// addresses -> no contention; workers never wait on the reducer -> no
// deadlock) and then does the fixed-order final sum (identical order to
// R8's k_final -> absmax 0.0).
__global__ void __launch_bounds__(256)
k_fused(const int* __restrict__ target,
        const ull* __restrict__ mPC,
        const ull* __restrict__ mGT0,
        const ull* __restrict__ mG255,
        const int* __restrict__ tminPart,
        float* __restrict__ partialB,
        float* __restrict__ out) {
    const int blk = blockIdx.x;
    const int i = threadIdx.x;

    if (blk == NCOL) {
        // ---- reducer block: poll + fixed-order reduction ----
        float acc = 0.0f;
        for (int q = 0; q < NCOL / 256; ++q) {
            int s = i + q * 256;           // same order as R8's k_final loop
            float v;
            for (;;) {
                v = __hip_atomic_load(&partialB[s], __ATOMIC_ACQUIRE,
                                      __HIP_MEMORY_SCOPE_AGENT);
                if (v > -0.5f) break;
                __builtin_amdgcn_s_sleep(16);
            }
            acc += v;
        }
        __shared__ float sred[256];
        sred[i] = acc;
        __syncthreads();
        for (int st = 128; st > 0; st >>= 1) {
            if (i < st) sred[i] += sred[i + st];
            __syncthreads();
        }
        if (i == 0) out[0] = sred[0] * (1.0f / (float)NPIX);  // /2^19: exact
        return;
    }

    // ---- worker block: R8 body, 1 column ----
    const int b = blk >> 8, j = blk & 255;
    const int wv = i >> 6, ln = i & 63;

    __shared__ float s_p[HH], s_g[HH];
    __shared__ ull   cshP[4], cshG[4];
    __shared__ int   stw[4];
    __shared__ float sws[4];

    // tmin = min of the 256 k_masks partials
    {
        int v = tminPart[i];
        for (int off = 32; off > 0; off >>= 1) v = min(v, __shfl_down(v, off));
        if (ln == 0) stw[wv] = v;
    }
    __syncthreads();
    const int tmin = min(min(stw[0], stw[1]), min(stw[2], stw[3]));
    const bool allpos = (tmin > 0);

    // row i's masks: 4 consecutive ULLs each -> coalesced loads
    ull wp[4], wg[4];
    {
        const ull* pP = mPC   + ((size_t)b * HH + i) * 4;
        const ull* p0 = mGT0  + ((size_t)b * HH + i) * 4;
        const ull* p2 = mG255 + ((size_t)b * HH + i) * 4;
#pragma unroll
        for (int k = 0; k < 4; ++k) {
            wp[k] = pP[k];
            ull g = p0[k];
            if (!allpos) g &= ~p2[k];      // 255 -> tmin==0 -> not >0
            wg[k] = g;
        }
    }

    float psum = column_partial(target, b, j, i, tmin, wp, wg,
                                s_p, s_g, cshP, cshG, sws);
    if (i == 0)
        __hip_atomic_store(&partialB[blk], psum, __ATOMIC_RELEASE,
                           __HIP_MEMORY_SCOPE_AGENT);
}

// ---------------------------------------------------------------------------
extern "C" void kernel_launch(void* const* d_in, const int* in_sizes, int n_in,
                              void* d_out, int out_size, void* d_ws, size_t ws_size,
                              hipStream_t stream) {
    const float* preds  = (const float*)d_in[0];
    const int*   target = (const int*)d_in[1];
    float* out = (float*)d_out;

    // ws layout: 3 mask arrays, tmin partials (256), column partials (2048)
    ull* mPC   = (ull*)d_ws;                         // 8*256*4 ULL
    ull* mGT0  = mPC  + (size_t)BB * HH * 4;
    ull* mG255 = mGT0 + (size_t)BB * HH * 4;
    int*   tminPart = (int*)(mG255 + (size_t)BB * HH * 4);     // 256 ints
    float* partialB = (float*)(tminPart + 256);                // NCOL floats

    k_masks<<<256, 256, 0, stream>>>(preds, target, mPC, mGT0, mG255,
                                     tminPart, partialB);
    k_fused<<<FGRID, 256, 0, stream>>>(target, mPC, mGT0, mG255, tminPart,
                                       partialB, out);
}